// Round 10
// baseline (507.819 us; speedup 1.0000x reference)
//
#include <hip/hip_runtime.h>
#include <cstdint>

typedef unsigned short u16;
typedef unsigned int   u32;
typedef unsigned long long u64;

typedef _Float16 f16x2 __attribute__((ext_vector_type(2)));
typedef _Float16 f16x8 __attribute__((ext_vector_type(8)));
typedef float    f32x4 __attribute__((ext_vector_type(4)));

// pack two f32 into fp16x2 bits (RTZ fine: inputs exactly fp16-representable)
__device__ __forceinline__ u32 cvt_pk(float a, float b) {
    return __builtin_bit_cast(u32, __builtin_amdgcn_cvt_pkrtz(a, b));
}

// Unpack one int32 (8 nibbles LSB-first along K) -> dequantized f16x8 in the
// k-order [0,4,1,5,2,6,3,7]. Exact math, verified R1-R9 (absmax 0.0625).
__device__ __forceinline__ f16x8 unpack_dq(u32 q, f16x2 cz, f16x2 cs) {
    const u32 b0 = (q & 0x000F000Fu) | 0x64006400u;         // nib0,nib4
    const u32 b1 = ((q >> 4) & 0x000F000Fu) | 0x64006400u;  // nib1,nib5
    const u32 b2 = ((q >> 8) & 0x000F000Fu) | 0x64006400u;  // nib2,nib6
    const u32 b3 = ((q >> 12) & 0x000F000Fu) | 0x64006400u; // nib3,nib7
    const f16x2 w0 = (__builtin_bit_cast(f16x2, b0) - cz) * cs;
    const f16x2 w1 = (__builtin_bit_cast(f16x2, b1) - cz) * cs;
    const f16x2 w2 = (__builtin_bit_cast(f16x2, b2) - cz) * cs;
    const f16x2 w3 = (__builtin_bit_cast(f16x2, b3) - cz) * cs;
    uint4 w;
    w.x = __builtin_bit_cast(u32, w0);
    w.y = __builtin_bit_cast(u32, w1);
    w.z = __builtin_bit_cast(u32, w2);
    w.w = __builtin_bit_cast(u32, w3);
    return __builtin_bit_cast(f16x8, w);
}

__device__ __forceinline__ void load_lds16(const void* g, void* l) {
    __builtin_amdgcn_global_load_lds(
        (const __attribute__((address_space(1))) void*)g,
        (__attribute__((address_space(3))) void*)l,
        16, 0, 0);
}

// =====================================================================
// Prepass A: X f32 [8192,4096] -> Xh f16, tiled LDS-image layout.
// (unchanged) u16 off = r*64 + sg*8, sg = g ^ (r&7), granule g holds
// k-local [8g,8g+8) in order [0,4,1,5,2,6,3,7].
// =====================================================================
__global__ __launch_bounds__(256) void gptq_prepass(
    const float* __restrict__ X, u16* __restrict__ Xh)
{
    const u32 tile = blockIdx.x;          // 0..4095 : mt = tile>>6, t = tile&63
    const u32 mt = tile >> 6, t = tile & 63;
    const float* bsrc = X + ((u64)mt << 19) + t * 64;
    u16* bdst = Xh + ((u64)tile << 13);
#pragma unroll
    for (int pass = 0; pass < 4; ++pass) {
        const u32 idx = pass * 256 + threadIdx.x;       // 0..1023
        const u32 r = idx >> 3, sg = idx & 7, g = sg ^ (r & 7);
        const float* s = bsrc + ((u64)r << 12) + g * 8;
        const float4 f0 = *(const float4*)s;
        const float4 f1 = *(const float4*)(s + 4);
        uint4 w;
        w.x = cvt_pk(f0.x, f1.x);
        w.y = cvt_pk(f0.y, f1.y);
        w.z = cvt_pk(f0.z, f1.z);
        w.w = cvt_pk(f0.w, f1.w);
        *(uint4*)(bdst + idx * 8) = w;
    }
}

// =====================================================================
// Prepass B: QW -> Bt, fully dequantized f16 in MFMA fragment layout.
// (unchanged from R8, measured win) Bt[(chunk>>2)*256 + n16][quad*16+n15][8]
// =====================================================================
__global__ __launch_bounds__(256) void gptq_dequantB(
    const int* __restrict__ QW, const int* __restrict__ QZ,
    const float* __restrict__ SC, u16* __restrict__ Bt)
{
    __shared__ int tile[64][65];
    const u32 bkq = blockIdx.x;           // 0..7   (64 chunks each)
    const u32 bn  = blockIdx.y;           // 0..63  (64 cols each)
    const u32 t = threadIdx.x;
    const u32 r = t >> 4, c4 = (t & 15) * 4;
#pragma unroll
    for (int p = 0; p < 4; ++p) {
        const u32 row = p * 16 + r;       // n-local
        const int4 v = *(const int4*)(QW + (u64)(bn * 64 + row) * 512
                                         + bkq * 64 + c4);
        tile[row][c4 + 0] = v.x; tile[row][c4 + 1] = v.y;
        tile[row][c4 + 2] = v.z; tile[row][c4 + 3] = v.w;
    }
    __syncthreads();
    char* BtB = (char*)Bt;
#pragma unroll
    for (int p = 0; p < 4; ++p) {
        const u32 kql = p * 16 + r;
        const u32 chunk = bkq * 64 + kql;           // 0..511
        const u32 g = chunk >> 4;                   // group (k/128)
        const u32 quad = chunk & 3;
        const u64 base = ((u64)((chunk >> 2) * 256)) * 1024 + quad * 256;
#pragma unroll
        for (int e = 0; e < 4; ++e) {
            const u32 n = bn * 64 + c4 + e;
            const u32 q = (u32)tile[c4 + e][kql];
            const float s = SC[g * 4096 + n];
            const int zw = QZ[g * 512 + (n >> 3)];
            const int z = (zw >> ((n & 7) * 4)) & 0xF;
            const _Float16 hs = (_Float16)s;
            const _Float16 hz = (_Float16)(float)(1024 + z);
            const f16x8 v = unpack_dq(q, (f16x2){hz, hz}, (f16x2){hs, hs});
            *(f16x8*)(BtB + base + (u64)(n >> 4) * 1024 + (n & 15) * 16) = v;
        }
    }
}

// =====================================================================
// Main GEMM: zero-dequant path retiled for 3 waves/SIMD (TLP was the
// binding constraint: R9 showed MFMA busy is at ~95% of the shape's
// achievable rate; the 48% stall needs more waves, not deeper pipes).
// Wave tile 64x64 (acc[4][4] = 64 AGPR), block 128x128 (2x2 waves),
// grid 64x32, __launch_bounds__(256,3), LDS 2x16KB.
// B prefetch at ks granularity (bq[2][4] = 32 arch regs) to fit the
// 170-reg budget: load ks1(t) under COMPUTE(ks0), ks0(t+1) under
// COMPUTE(ks1). Counted vmcnt keeps the STAGE queue un-drained.
// =====================================================================
__global__ __launch_bounds__(256, 3) void gptq_gemm_dq(
    const u16* __restrict__ Xh,     // [M/128][K/64][128][64] f16, swizzled
    const u16* __restrict__ Bt,     // fragment-layout f16 B (32 MB)
    const float* __restrict__ BIAS, // [N] f32
    float* __restrict__ Y)          // [M, N] f32
{
    constexpr int N = 4096, NT = 64;

    __shared__ __align__(16) u16 Alds[2][128 * 64];   // 2 x 16 KB

    const int tid  = threadIdx.x;
    const int lane = tid & 63;
    const int wid  = tid >> 6;

    const int mt = blockIdx.x;       // 0..63
    const int m0 = mt * 128;
    const int n0 = blockIdx.y * 128; // gridDim.y = 32
    const int wm = (wid >> 1) * 64;  // wave m-offset
    const int wn = (wid & 1) * 64;   // wave n-offset

    f32x4 acc[4][4];
#pragma unroll
    for (int i = 0; i < 4; i++)
#pragma unroll
        for (int j = 0; j < 4; j++)
            acc[i][j] = (f32x4){0.f, 0.f, 0.f, 0.f};

    const int fr   = lane & 15;
    const int quad = lane >> 4;
    const int fr7  = fr & 7;

    // A staging: per-lane global source (layout == LDS image), linear LDS dest
    const char* xsrc = (const char*)Xh + (((u64)mt * NT) << 14)
                     + wid * 4096 + lane * 16;

    // B fragments: byte = ((t*2+ks)<<18) + (nb16+ni)*1024 + lane*16
    const int nb16 = (n0 >> 4) + (wid & 1) * 4;
    const char* btb = (const char*)Bt + (u64)nb16 * 1024 + lane * 16;

    f16x8 bq[2][4];           // [ks-slot][ni], static indices only

    auto STAGE = [&](int buf, int t) {                  // 4 DMA loads
        const char* s = xsrc + ((u64)t << 14);
        char* d = (char*)&Alds[buf][0] + wid * 4096;
#pragma unroll
        for (int i = 0; i < 4; i++)
            load_lds16(s + i * 1024, d + i * 1024);
    };

    auto FETCH_B_KS = [&](int t, int ks, int slot) {    // 4 coalesced b128
        const char* p = btb + ((u64)(t * 2 + ks) << 18);
#pragma unroll
        for (int ni = 0; ni < 4; ni++)
            bq[slot][ni] = *(const f16x8*)(p + ni * 1024);
    };

    auto COMPUTE_KS = [&](int buf, int ks, int slot) {  // 16 MFMAs
        const int gsw = ((ks * 4 + quad) ^ fr7) * 8;
        __builtin_amdgcn_s_setprio(1);
#pragma unroll
        for (int mi = 0; mi < 4; mi++) {
            const f16x8 af =
                *(const f16x8*)(&Alds[buf][(wm + mi * 16 + fr) * 64 + gsw]);
#pragma unroll
            for (int ni = 0; ni < 4; ni++)
                acc[mi][ni] = __builtin_amdgcn_mfma_f32_16x16x32_f16(
                    af, bq[slot][ni], acc[mi][ni], 0, 0, 0);
        }
        __builtin_amdgcn_s_setprio(0);
    };

    // ---- prologue: B(0,ks0):4, STAGE(0):4, STAGE(1):4 ----
    FETCH_B_KS(0, 0, 0);
    STAGE(0, 0);
    STAGE(1, 1);
    // B(0,ks0)+STAGE(0) landed; STAGE(1):4 stays in flight
    asm volatile("s_waitcnt vmcnt(4)\n\ts_barrier" ::: "memory");

    // ---- main loop: 32 iterations x 2 phases, uniform counts ----
    // Wrapped indices (&63) on the last iteration are harmless dead
    // loads/stages into buffers that are never read again.
    for (int t = 0; t < NT; t += 2) {
        // phase t (buf0)
        FETCH_B_KS(t, 1, 1);                 // 4: B ks1 of this step
        COMPUTE_KS(0, 0, 0);                 // bq[0] loaded last phase
        FETCH_B_KS((t + 1) & 63, 0, 0);      // 4: B ks0 of next step
        COMPUTE_KS(0, 1, 1);
        asm volatile("s_barrier" ::: "memory");          // buf0 consumed
        STAGE(0, (t + 2) & 63);              // 4 DMA
        // STAGE(t+1) must land; newer = Bks1:4 + Bks0:4 + STAGE:4 = 12
        asm volatile("s_waitcnt vmcnt(12)\n\ts_barrier" ::: "memory");

        // phase t+1 (buf1)
        FETCH_B_KS((t + 1) & 63, 1, 1);
        COMPUTE_KS(1, 0, 0);
        FETCH_B_KS((t + 2) & 63, 0, 0);
        COMPUTE_KS(1, 1, 1);
        asm volatile("s_barrier" ::: "memory");          // buf1 consumed
        STAGE(1, (t + 3) & 63);
        asm volatile("s_waitcnt vmcnt(12)\n\ts_barrier" ::: "memory");
    }

    // ---- epilogue: + bias. C/D map: col=lane&15, row=quad*4+reg ----
    const int cn  = lane & 15;
    const int q4r = quad * 4;
#pragma unroll
    for (int ni = 0; ni < 4; ni++) {
        const int col = n0 + wn + ni * 16 + cn;
        const float bz = BIAS[col];
#pragma unroll
        for (int mi = 0; mi < 4; mi++) {
            const int rbase = m0 + wm + mi * 16 + q4r;
#pragma unroll
            for (int r = 0; r < 4; r++) {
                Y[(u64)(rbase + r) * N + col] = acc[mi][ni][r] + bz;
            }
        }
    }
}

// =====================================================================
// Mid path (ws in [72,96) MB): exact R6 winner (measured 273us).
// =====================================================================
__global__ __launch_bounds__(256) void gptq_transpose(
    const int* __restrict__ QW, int* __restrict__ QWt)
{
    __shared__ int tile[64][65];
    const u32 bkq = blockIdx.x, bn = blockIdx.y;
    const u32 t = threadIdx.x;
    const u32 r = t >> 4, c4 = (t & 15) * 4;
#pragma unroll
    for (int p = 0; p < 4; ++p) {
        const u32 row = p * 16 + r;
        const int4 v = *(const int4*)(QW + (u64)(bn * 64 + row) * 512
                                         + bkq * 64 + c4);
        tile[row][c4 + 0] = v.x; tile[row][c4 + 1] = v.y;
        tile[row][c4 + 2] = v.z; tile[row][c4 + 3] = v.w;
    }
    __syncthreads();
#pragma unroll
    for (int p = 0; p < 4; ++p) {
        const u32 kql = p * 16 + r;
        int4 v;
        v.x = tile[c4 + 0][kql]; v.y = tile[c4 + 1][kql];
        v.z = tile[c4 + 2][kql]; v.w = tile[c4 + 3][kql];
        *(int4*)(QWt + (u64)(bkq * 64 + kql) * 4096 + bn * 64 + c4) = v;
    }
}

__global__ __launch_bounds__(256, 2) void gptq_gemm_dma(
    const u16* __restrict__ Xh, const int* __restrict__ QWt,
    const int* __restrict__ QZ, const float* __restrict__ SC,
    const float* __restrict__ BIAS, float* __restrict__ Y)
{
    constexpr int N = 4096, NT = 64;
    __shared__ __align__(16) u16 Alds[2][128 * 64];
    const int tid = threadIdx.x, lane = tid & 63, wid = tid >> 6;
    const int mt = blockIdx.x, m0 = mt * 128, n0 = blockIdx.y * 256;
    f32x4 acc[8][4];
#pragma unroll
    for (int i = 0; i < 8; i++)
#pragma unroll
        for (int j = 0; j < 4; j++) acc[i][j] = (f32x4){0.f, 0.f, 0.f, 0.f};
    const int fr = lane & 15, quad = lane >> 4, fr7 = fr & 7;
    const char* xsrc = (const char*)Xh + (((u64)mt * NT) << 14)
                     + wid * 4096 + lane * 16;
    const int nbase = n0 + wid * 64 + fr;
    const char* QWtB = (const char*)QWt;
    const u64 qtbase = (u64)((u32)(quad * 4096 + nbase) * 4u);
    int bq[2][8];
    float sf_st[4];
    int zw_st[4];
    f16x2 cs[4], cz[4];
    const int zsh = fr7 * 4;
    auto STAGE = [&](int buf, int t) {
        const char* s = xsrc + ((u64)t << 14);
        char* d = (char*)&Alds[buf][0] + wid * 4096;
#pragma unroll
        for (int i = 0; i < 4; i++) load_lds16(s + i * 1024, d + i * 1024);
    };
    auto FETCH_B = [&](int t, int nb) {
        const char* p = QWtB + ((u64)t << 17) + qtbase;
#pragma unroll
        for (int ni = 0; ni < 4; ni++) {
            bq[nb][ni * 2 + 0] = *(const int*)(p + ni * 64);
            bq[nb][ni * 2 + 1] = *(const int*)(p + 65536 + ni * 64);
        }
    };
    auto FETCH_SZ = [&](int g) {
#pragma unroll
        for (int ni = 0; ni < 4; ni++) {
            sf_st[ni] = SC[g * N + nbase + ni * 16];
            zw_st[ni] = QZ[g * (N / 8) + ((nbase + ni * 16) >> 3)];
        }
    };
    auto CONV_SZ = [&]() {
#pragma unroll
        for (int ni = 0; ni < 4; ni++) {
            const int z = (zw_st[ni] >> zsh) & 0xF;
            const _Float16 hs = (_Float16)sf_st[ni];
            const _Float16 hz = (_Float16)(float)(1024 + z);
            cs[ni] = (f16x2){hs, hs};
            cz[ni] = (f16x2){hz, hz};
        }
    };
    auto COMPUTE = [&](int buf, int nb) {
#pragma unroll
        for (int ks = 0; ks < 2; ks++) {
            f16x8 bfr[4];
#pragma unroll
            for (int ni = 0; ni < 4; ni++)
                bfr[ni] = unpack_dq((u32)bq[nb][ni * 2 + ks], cz[ni], cs[ni]);
            const int gsw = ((ks * 4 + quad) ^ fr7) * 8;
            __builtin_amdgcn_s_setprio(1);
#pragma unroll
            for (int mi = 0; mi < 8; mi++) {
                const f16x8 af =
                    *(const f16x8*)(&Alds[buf][(mi * 16 + fr) * 64 + gsw]);
#pragma unroll
                for (int ni = 0; ni < 4; ni++)
                    acc[mi][ni] = __builtin_amdgcn_mfma_f32_16x16x32_f16(
                        af, bfr[ni], acc[mi][ni], 0, 0, 0);
            }
            __builtin_amdgcn_s_setprio(0);
        }
    };
    FETCH_B(0, 0);
    FETCH_SZ(0);
    STAGE(0, 0);
    STAGE(1, 1);
    CONV_SZ();
    asm volatile("s_waitcnt vmcnt(4)\n\ts_barrier" ::: "memory");
    for (int t = 0; t <= 60; t += 2) {
        FETCH_B(t + 1, 1);
        FETCH_SZ((t >> 1) + 1);
        COMPUTE(0, 0);
        asm volatile("s_barrier" ::: "memory");
        STAGE(0, t + 2);
        asm volatile("s_waitcnt vmcnt(20)\n\ts_barrier" ::: "memory");
        FETCH_B(t + 2, 0);
        COMPUTE(1, 1);
        CONV_SZ();
        asm volatile("s_barrier" ::: "memory");
        STAGE(1, t + 3);
        asm volatile("s_waitcnt vmcnt(12)\n\ts_barrier" ::: "memory");
    }
    FETCH_B(63, 1);
    COMPUTE(0, 0);
    asm volatile("s_waitcnt vmcnt(8)\n\ts_barrier" ::: "memory");
    COMPUTE(1, 1);
    const int cn = lane & 15, q4r = quad * 4;
#pragma unroll
    for (int ni = 0; ni < 4; ni++) {
        const int col = n0 + wid * 64 + ni * 16 + cn;
        const float bz = BIAS[col];
#pragma unroll
        for (int mi = 0; mi < 8; mi++) {
            const int rbase = m0 + mi * 16 + q4r;
#pragma unroll
            for (int r = 0; r < 4; r++)
                Y[(u64)(rbase + r) * N + col] = acc[mi][ni][r] + bz;
        }
    }
}

// =====================================================================
// Fallback (no ws): R1's verified kernel, unchanged (original inputs).
// =====================================================================
__global__ __launch_bounds__(256, 2) void gptq_gemm_fb(
    const float* __restrict__ X, const int* __restrict__ QW,
    const int* __restrict__ QZ, const float* __restrict__ SC,
    const float* __restrict__ BIAS, float* __restrict__ Y)
{
    constexpr int N = 4096, K = 4096, KB = 512, NT = 64;
    __shared__ __align__(16) u16 Alds[2][128 * 64];
    __shared__ __align__(16) u16 Blds[2][128 * 64];
    const int tid = threadIdx.x, lane = tid & 63, wid = tid >> 6;
    const int m0 = blockIdx.x * 128, n0 = blockIdx.y * 128;
    f32x4 acc[4][4];
#pragma unroll
    for (int i = 0; i < 4; i++)
#pragma unroll
        for (int j = 0; j < 4; j++) acc[i][j] = (f32x4){0.f, 0.f, 0.f, 0.f};
    const int wm = (wid >> 1) * 64, wn = (wid & 1) * 64;
    const int lrowA = tid >> 3;
    const float* gA = X + (u64)(m0 + lrowA) * K + (tid & 7) * 8;
    const int sA = ((tid & 7) ^ (lrowA & 7)) * 8;
    const int nl = tid >> 1, kq0 = (tid & 1) * 4;
    const int nglob = n0 + nl;
    const int* qrow = QW + (u64)nglob * KB;
    const int nl7 = nl & 7, zsh = (nglob & 7) * 4;
    const float* scp = SC + nglob;
    const int* qzp = QZ + (nglob >> 3);
    const int fr = lane & 15, quad = lane >> 4, fr7 = fr & 7;
    float4 af32[8];
    int4 q4;
    float sf;
    int zw;
    auto FETCH = [&](int t) {
        const int kt = t * 64;
#pragma unroll
        for (int i = 0; i < 4; i++) {
            const float* pa = gA + (u64)i * 32 * K + kt;
            af32[2 * i] = *(const float4*)pa;
            af32[2 * i + 1] = *(const float4*)(pa + 4);
        }
        q4 = *(const int4*)(qrow + (kt >> 3) + kq0);
        const int g = t >> 1;
        sf = scp[g * N];
        zw = qzp[g * (N / 8)];
    };
    auto STORE = [&](int buf) {
#pragma unroll
        for (int i = 0; i < 4; i++) {
            const float4 f0 = af32[2 * i], f1 = af32[2 * i + 1];
            uint4 w;
            w.x = cvt_pk(f0.x, f1.x); w.y = cvt_pk(f0.y, f1.y);
            w.z = cvt_pk(f0.z, f1.z); w.w = cvt_pk(f0.w, f1.w);
            *(uint4*)(&Alds[buf][(i * 32 + lrowA) * 64 + sA]) = w;
        }
        const int z = (zw >> zsh) & 0xF;
        const _Float16 hs = (_Float16)sf;
        const _Float16 hz = (_Float16)(float)(1024 + z);
        const f16x2 cs2 = {hs, hs}, cz2 = {hz, hz};
        const int qv[4] = {q4.x, q4.y, q4.z, q4.w};
#pragma unroll
        for (int c = 0; c < 4; c++) {
            const f16x8 wv = unpack_dq((u32)qv[c], cz2, cs2);
            const int gran = ((kq0 + c) ^ nl7) * 8;
            *(f16x8*)(&Blds[buf][nl * 64 + gran]) = wv;
        }
    };
    auto COMPUTE = [&](int buf) {
#pragma unroll
        for (int ks = 0; ks < 2; ks++) {
            const int gsw = ((ks * 4 + quad) ^ fr7) * 8;
            f16x8 af[4], bfr[4];
#pragma unroll
            for (int i = 0; i < 4; i++)
                af[i] = *(const f16x8*)(&Alds[buf][(wm + i * 16 + fr) * 64 + gsw]);
#pragma unroll
            for (int i = 0; i < 4; i++)
                bfr[i] = *(const f16x8*)(&Blds[buf][(wn + i * 16 + fr) * 64 + gsw]);
#pragma unroll
            for (int mi = 0; mi < 4; mi++)
#pragma unroll
                for (int ni = 0; ni < 4; ni++)
                    acc[mi][ni] = __builtin_amdgcn_mfma_f32_16x16x32_f16(
                        af[mi], bfr[ni], acc[mi][ni], 0, 0, 0);
        }
    };
    FETCH(0); STORE(0); __syncthreads();
#pragma unroll 2
    for (int t = 0; t < NT; ++t) {
        const int cur = t & 1;
        if (t + 1 < NT) FETCH(t + 1);
        COMPUTE(cur);
        if (t + 1 < NT) STORE(cur ^ 1);
        __syncthreads();
    }
    const int cn = lane & 15, q4r = quad * 4;
#pragma unroll
    for (int ni = 0; ni < 4; ni++) {
        const int col = n0 + wn + ni * 16 + cn;
        const float bz = BIAS[col];
#pragma unroll
        for (int mi = 0; mi < 4; mi++) {
            const int rbase = m0 + wm + mi * 16 + q4r;
#pragma unroll
            for (int r = 0; r < 4; r++)
                Y[(u64)(rbase + r) * N + col] = acc[mi][ni][r] + bz;
        }
    }
}

extern "C" void kernel_launch(void* const* d_in, const int* in_sizes, int n_in,
                              void* d_out, int out_size, void* d_ws, size_t ws_size,
                              hipStream_t stream) {
    const float* X    = (const float*)d_in[0];   // x       [2,4096,4096] f32
    const int*   QW   = (const int*)d_in[1];     // qweight [4096,512] int32
    const int*   QZ   = (const int*)d_in[2];     // qzeros  [32,512] int32
    const float* SC   = (const float*)d_in[3];   // scales  [32,4096] f32
    const float* BIAS = (const float*)d_in[4];   // bias    [4096] f32
    float* Y = (float*)d_out;                    // [8192,4096] f32

    const size_t needXh = (size_t)8192 * 4096 * sizeof(u16);       // 64 MiB
    const size_t needNew = needXh + (size_t)4096 * 4096 * 2;       // + 32 MiB
    const size_t needMid = needXh + (size_t)512 * 4096 * 4;        // + 8 MiB
    if (ws_size >= needNew) {
        u16* Xh = (u16*)d_ws;
        u16* Bt = (u16*)((char*)d_ws + needXh);
        gptq_prepass<<<4096, 256, 0, stream>>>(X, Xh);
        gptq_dequantB<<<dim3(8, 64), 256, 0, stream>>>(QW, QZ, SC, Bt);
        dim3 grid(64, 32, 1);                               // M/128 x N/128
        gptq_gemm_dq<<<grid, 256, 0, stream>>>(Xh, Bt, BIAS, Y);
    } else if (ws_size >= needMid) {
        u16* Xh  = (u16*)d_ws;
        int* QWt = (int*)((char*)d_ws + needXh);
        gptq_prepass<<<4096, 256, 0, stream>>>(X, Xh);
        gptq_transpose<<<dim3(8, 64), 256, 0, stream>>>(QW, QWt);
        dim3 grid(64, 16, 1);                               // M/128 x N/256
        gptq_gemm_dma<<<grid, 256, 0, stream>>>(Xh, QWt, QZ, SC, BIAS, Y);
    } else {
        dim3 grid(64, 32, 1);                               // M/128 x N/128
        gptq_gemm_fb<<<grid, 256, 0, stream>>>(X, QW, QZ, SC, BIAS, Y);
    }
}

// Round 11
// 476.767 us; speedup vs baseline: 1.0651x; 1.0651x over previous
//
#include <hip/hip_runtime.h>
#include <cstdint>

typedef unsigned short u16;
typedef unsigned int   u32;
typedef unsigned long long u64;

typedef _Float16 f16x2 __attribute__((ext_vector_type(2)));
typedef _Float16 f16x8 __attribute__((ext_vector_type(8)));
typedef float    f32x4 __attribute__((ext_vector_type(4)));

// pack two f32 into fp16x2 bits (RTZ fine: inputs exactly fp16-representable)
__device__ __forceinline__ u32 cvt_pk(float a, float b) {
    return __builtin_bit_cast(u32, __builtin_amdgcn_cvt_pkrtz(a, b));
}

// Unpack one int32 (8 nibbles LSB-first along K) -> dequantized f16x8 in the
// k-order [0,4,1,5,2,6,3,7]. Exact math, verified R1-R10 (absmax 0.0625).
__device__ __forceinline__ f16x8 unpack_dq(u32 q, f16x2 cz, f16x2 cs) {
    const u32 b0 = (q & 0x000F000Fu) | 0x64006400u;         // nib0,nib4
    const u32 b1 = ((q >> 4) & 0x000F000Fu) | 0x64006400u;  // nib1,nib5
    const u32 b2 = ((q >> 8) & 0x000F000Fu) | 0x64006400u;  // nib2,nib6
    const u32 b3 = ((q >> 12) & 0x000F000Fu) | 0x64006400u; // nib3,nib7
    const f16x2 w0 = (__builtin_bit_cast(f16x2, b0) - cz) * cs;
    const f16x2 w1 = (__builtin_bit_cast(f16x2, b1) - cz) * cs;
    const f16x2 w2 = (__builtin_bit_cast(f16x2, b2) - cz) * cs;
    const f16x2 w3 = (__builtin_bit_cast(f16x2, b3) - cz) * cs;
    uint4 w;
    w.x = __builtin_bit_cast(u32, w0);
    w.y = __builtin_bit_cast(u32, w1);
    w.z = __builtin_bit_cast(u32, w2);
    w.w = __builtin_bit_cast(u32, w3);
    return __builtin_bit_cast(f16x8, w);
}

__device__ __forceinline__ void load_lds16(const void* g, void* l) {
    __builtin_amdgcn_global_load_lds(
        (const __attribute__((address_space(1))) void*)g,
        (__attribute__((address_space(3))) void*)l,
        16, 0, 0);
}

// =====================================================================
// Fused prepass (one launch):
//   blocks [0,4096): X f32 -> Xh f16 tiled LDS-image layout (as before)
//   blocks [4096,4608): QW -> Bt fully-dequantized f16 fragment layout
// Mid path launches this with grid=4096 (B part simply absent).
// =====================================================================
__global__ __launch_bounds__(256) void gptq_prep_fused(
    const float* __restrict__ X, u16* __restrict__ Xh,
    const int* __restrict__ QW, const int* __restrict__ QZ,
    const float* __restrict__ SC, u16* __restrict__ Bt)
{
    __shared__ int tile[64][65];
    if (blockIdx.x < 4096) {
        // ---- prepass A ----
        const u32 tl = blockIdx.x;        // mt = tl>>6, t = tl&63
        const u32 mt = tl >> 6, t = tl & 63;
        const float* bsrc = X + ((u64)mt << 19) + t * 64;
        u16* bdst = Xh + ((u64)tl << 13);
#pragma unroll
        for (int pass = 0; pass < 4; ++pass) {
            const u32 idx = pass * 256 + threadIdx.x;   // 0..1023
            const u32 r = idx >> 3, sg = idx & 7, g = sg ^ (r & 7);
            const float* s = bsrc + ((u64)r << 12) + g * 8;
            const float4 f0 = *(const float4*)s;
            const float4 f1 = *(const float4*)(s + 4);
            uint4 w;
            w.x = cvt_pk(f0.x, f1.x);
            w.y = cvt_pk(f0.y, f1.y);
            w.z = cvt_pk(f0.z, f1.z);
            w.w = cvt_pk(f0.w, f1.w);
            *(uint4*)(bdst + idx * 8) = w;
        }
    } else {
        // ---- prepass B: dequantized fragment-layout Bt ----
        const u32 bid = blockIdx.x - 4096;    // 0..511
        const u32 bkq = bid >> 6;             // 0..7
        const u32 bn  = bid & 63;             // 0..63
        const u32 t = threadIdx.x;
        const u32 r = t >> 4, c4 = (t & 15) * 4;
#pragma unroll
        for (int p = 0; p < 4; ++p) {
            const u32 row = p * 16 + r;       // n-local
            const int4 v = *(const int4*)(QW + (u64)(bn * 64 + row) * 512
                                             + bkq * 64 + c4);
            tile[row][c4 + 0] = v.x; tile[row][c4 + 1] = v.y;
            tile[row][c4 + 2] = v.z; tile[row][c4 + 3] = v.w;
        }
        __syncthreads();
        char* BtB = (char*)Bt;
#pragma unroll
        for (int p = 0; p < 4; ++p) {
            const u32 kql = p * 16 + r;
            const u32 chunk = bkq * 64 + kql;           // 0..511
            const u32 g = chunk >> 4;                   // group (k/128)
            const u32 quad = chunk & 3;
            const u64 base = ((u64)((chunk >> 2) * 256)) * 1024 + quad * 256;
#pragma unroll
            for (int e = 0; e < 4; ++e) {
                const u32 n = bn * 64 + c4 + e;
                const u32 q = (u32)tile[c4 + e][kql];
                const float s = SC[g * 4096 + n];
                const int zw = QZ[g * 512 + (n >> 3)];
                const int z = (zw >> ((n & 7) * 4)) & 0xF;
                const _Float16 hs = (_Float16)s;
                const _Float16 hz = (_Float16)(float)(1024 + z);
                const f16x8 v = unpack_dq(q, (f16x2){hz, hz}, (f16x2){hs, hs});
                *(f16x8*)(BtB + base + (u64)(n >> 4) * 1024 + (n & 15) * 16) = v;
            }
        }
    }
}

// =====================================================================
// Main GEMM: R8's proven geometry (128x256 block, wave 128x64, acc[8][4],
// A-DMA, B direct from pre-dequantized Bt) with a 3-buffer LDS pipeline
// and ONE barrier per K-step:
//   phase t: FETCH_B(t+1) ; STAGE(buf[(t+2)%3], t+2) ; COMPUTE(buf[t%3])
//            ; vmcnt(12) + s_barrier
// The barrier is simultaneously the read-before-overwrite guard (phase
// t+1 stages into buf[t%3]) and, with vmcnt(12), the write-before-read
// guard for tile t+1. Barrier count halves vs R8 (64 vs 128); the DMA
// queue never drains (uniform 12 newest ops stay in flight).
// =====================================================================
__global__ __launch_bounds__(256, 2) void gptq_gemm_dq(
    const u16* __restrict__ Xh,     // [M/128][K/64][128][64] f16, swizzled
    const u16* __restrict__ Bt,     // fragment-layout f16 B (32 MB)
    const float* __restrict__ BIAS, // [N] f32
    float* __restrict__ Y)          // [M, N] f32
{
    constexpr int N = 4096, NT = 64;

    __shared__ __align__(16) u16 Alds[3][128 * 64];   // 3 x 16 KB

    const int tid  = threadIdx.x;
    const int lane = tid & 63;
    const int wid  = tid >> 6;

    const int mt = blockIdx.x;       // 0..63
    const int m0 = mt * 128;
    const int n0 = blockIdx.y * 256; // gridDim.y = 16

    f32x4 acc[8][4];
#pragma unroll
    for (int i = 0; i < 8; i++)
#pragma unroll
        for (int j = 0; j < 4; j++)
            acc[i][j] = (f32x4){0.f, 0.f, 0.f, 0.f};

    const int fr   = lane & 15;
    const int quad = lane >> 4;
    const int fr7  = fr & 7;

    // A staging: per-lane global source (layout == LDS image), linear LDS dest
    const char* xsrc = (const char*)Xh + (((u64)mt * NT) << 14)
                     + wid * 4096 + lane * 16;

    // B fragments: byte = ((t*2+ks)<<18) + (nb16+ni)*1024 + lane*16
    const int nb16 = (n0 >> 4) + wid * 4;
    const char* btb = (const char*)Bt + (u64)nb16 * 1024 + lane * 16;

    f16x8 bq[2][2][4];        // [slot][ks][ni], static indices only

    auto STAGE = [&](int buf, int t) {                  // 4 DMA loads
        const char* s = xsrc + ((u64)t << 14);
        char* d = (char*)&Alds[buf][0] + wid * 4096;
#pragma unroll
        for (int i = 0; i < 4; i++)
            load_lds16(s + i * 1024, d + i * 1024);
    };

    auto FETCH_B = [&](int t, int nb) {                 // 8 coalesced b128
#pragma unroll
        for (int ks = 0; ks < 2; ks++) {
            const char* p = btb + ((u64)(t * 2 + ks) << 18);
#pragma unroll
            for (int ni = 0; ni < 4; ni++)
                bq[nb][ks][ni] = *(const f16x8*)(p + ni * 1024);
        }
    };

    auto COMPUTE = [&](int buf, int nb) {
#pragma unroll
        for (int ks = 0; ks < 2; ks++) {
            const int gsw = ((ks * 4 + quad) ^ fr7) * 8;
            __builtin_amdgcn_s_setprio(1);
#pragma unroll
            for (int mi = 0; mi < 8; mi++) {
                const f16x8 af =
                    *(const f16x8*)(&Alds[buf][(mi * 16 + fr) * 64 + gsw]);
#pragma unroll
                for (int ni = 0; ni < 4; ni++)
                    acc[mi][ni] = __builtin_amdgcn_mfma_f32_16x16x32_f16(
                        af, bq[nb][ks][ni], acc[mi][ni], 0, 0, 0);
            }
            __builtin_amdgcn_s_setprio(0);
        }
    };

    // phase t: bufc=t%3, bufs=(t+2)%3, sc=t&1, sn=(t+1)&1
    auto PHASE = [&](int bufc, int bufs, int sc, int sn, int tn, int ts) {
        FETCH_B(tn, sn);                 // 8
        __builtin_amdgcn_sched_barrier(0);
        STAGE(bufs, ts);                 // 4 DMA
        __builtin_amdgcn_sched_barrier(0);
        COMPUTE(bufc, sc);
        // STAGE(t+1) landed; newest 12 = FB(tn):8 + STAGE(ts):4 in flight
        asm volatile("s_waitcnt vmcnt(12)\n\ts_barrier" ::: "memory");
    };

    // ---- prologue: FB(0):8, STAGE(0):4, STAGE(1):4 ----
    FETCH_B(0, 0);
    __builtin_amdgcn_sched_barrier(0);
    STAGE(0, 0);
    STAGE(1, 1);
    __builtin_amdgcn_sched_barrier(0);
    // FB(0)+STAGE(0) landed; STAGE(1):4 stays in flight
    asm volatile("s_waitcnt vmcnt(4)\n\ts_barrier" ::: "memory");

    // ---- phases 0..59 (period-6 unroll: buf t%3, slot t&1) ----
    for (int t0 = 0; t0 < 60; t0 += 6) {
        PHASE(0, 2, 0, 1, t0 + 1, t0 + 2);   // t0+0
        PHASE(1, 0, 1, 0, t0 + 2, t0 + 3);   // t0+1
        PHASE(2, 1, 0, 1, t0 + 3, t0 + 4);   // t0+2
        PHASE(0, 2, 1, 0, t0 + 4, t0 + 5);   // t0+3
        PHASE(1, 0, 0, 1, t0 + 5, t0 + 6);   // t0+4
        PHASE(2, 1, 1, 0, t0 + 6, t0 + 7);   // t0+5
    }

    // ---- peeled phases 60..63 (wrapped stage/fetch targets are dead) ----
    PHASE(0, 2, 0, 1, 61, 62);               // t=60
    PHASE(1, 0, 1, 0, 62, 63);               // t=61
    PHASE(2, 1, 0, 1, 63, 0);                // t=62 (dead stage tile 0)
    COMPUTE(0, 1);                           // t=63

    // ---- epilogue: + bias. C/D map: col=lane&15, row=quad*4+reg ----
    const int cn  = lane & 15;
    const int q4r = quad * 4;
#pragma unroll
    for (int ni = 0; ni < 4; ni++) {
        const int col = n0 + wid * 64 + ni * 16 + cn;
        const float bz = BIAS[col];
#pragma unroll
        for (int mi = 0; mi < 8; mi++) {
            const int rbase = m0 + mi * 16 + q4r;
#pragma unroll
            for (int r = 0; r < 4; r++) {
                Y[(u64)(rbase + r) * N + col] = acc[mi][ni][r] + bz;
            }
        }
    }
}

// =====================================================================
// Mid path (ws in [72,96) MB): exact R6 winner (measured 273us).
// =====================================================================
__global__ __launch_bounds__(256) void gptq_transpose(
    const int* __restrict__ QW, int* __restrict__ QWt)
{
    __shared__ int tile[64][65];
    const u32 bkq = blockIdx.x, bn = blockIdx.y;
    const u32 t = threadIdx.x;
    const u32 r = t >> 4, c4 = (t & 15) * 4;
#pragma unroll
    for (int p = 0; p < 4; ++p) {
        const u32 row = p * 16 + r;
        const int4 v = *(const int4*)(QW + (u64)(bn * 64 + row) * 512
                                         + bkq * 64 + c4);
        tile[row][c4 + 0] = v.x; tile[row][c4 + 1] = v.y;
        tile[row][c4 + 2] = v.z; tile[row][c4 + 3] = v.w;
    }
    __syncthreads();
#pragma unroll
    for (int p = 0; p < 4; ++p) {
        const u32 kql = p * 16 + r;
        int4 v;
        v.x = tile[c4 + 0][kql]; v.y = tile[c4 + 1][kql];
        v.z = tile[c4 + 2][kql]; v.w = tile[c4 + 3][kql];
        *(int4*)(QWt + (u64)(bkq * 64 + kql) * 4096 + bn * 64 + c4) = v;
    }
}

__global__ __launch_bounds__(256, 2) void gptq_gemm_dma(
    const u16* __restrict__ Xh, const int* __restrict__ QWt,
    const int* __restrict__ QZ, const float* __restrict__ SC,
    const float* __restrict__ BIAS, float* __restrict__ Y)
{
    constexpr int N = 4096, NT = 64;
    __shared__ __align__(16) u16 Alds[2][128 * 64];
    const int tid = threadIdx.x, lane = tid & 63, wid = tid >> 6;
    const int mt = blockIdx.x, m0 = mt * 128, n0 = blockIdx.y * 256;
    f32x4 acc[8][4];
#pragma unroll
    for (int i = 0; i < 8; i++)
#pragma unroll
        for (int j = 0; j < 4; j++) acc[i][j] = (f32x4){0.f, 0.f, 0.f, 0.f};
    const int fr = lane & 15, quad = lane >> 4, fr7 = fr & 7;
    const char* xsrc = (const char*)Xh + (((u64)mt * NT) << 14)
                     + wid * 4096 + lane * 16;
    const int nbase = n0 + wid * 64 + fr;
    const char* QWtB = (const char*)QWt;
    const u64 qtbase = (u64)((u32)(quad * 4096 + nbase) * 4u);
    int bq[2][8];
    float sf_st[4];
    int zw_st[4];
    f16x2 cs[4], cz[4];
    const int zsh = fr7 * 4;
    auto STAGE = [&](int buf, int t) {
        const char* s = xsrc + ((u64)t << 14);
        char* d = (char*)&Alds[buf][0] + wid * 4096;
#pragma unroll
        for (int i = 0; i < 4; i++) load_lds16(s + i * 1024, d + i * 1024);
    };
    auto FETCH_B = [&](int t, int nb) {
        const char* p = QWtB + ((u64)t << 17) + qtbase;
#pragma unroll
        for (int ni = 0; ni < 4; ni++) {
            bq[nb][ni * 2 + 0] = *(const int*)(p + ni * 64);
            bq[nb][ni * 2 + 1] = *(const int*)(p + 65536 + ni * 64);
        }
    };
    auto FETCH_SZ = [&](int g) {
#pragma unroll
        for (int ni = 0; ni < 4; ni++) {
            sf_st[ni] = SC[g * N + nbase + ni * 16];
            zw_st[ni] = QZ[g * (N / 8) + ((nbase + ni * 16) >> 3)];
        }
    };
    auto CONV_SZ = [&]() {
#pragma unroll
        for (int ni = 0; ni < 4; ni++) {
            const int z = (zw_st[ni] >> zsh) & 0xF;
            const _Float16 hs = (_Float16)sf_st[ni];
            const _Float16 hz = (_Float16)(float)(1024 + z);
            cs[ni] = (f16x2){hs, hs};
            cz[ni] = (f16x2){hz, hz};
        }
    };
    auto COMPUTE = [&](int buf, int nb) {
#pragma unroll
        for (int ks = 0; ks < 2; ks++) {
            f16x8 bfr[4];
#pragma unroll
            for (int ni = 0; ni < 4; ni++)
                bfr[ni] = unpack_dq((u32)bq[nb][ni * 2 + ks], cz[ni], cs[ni]);
            const int gsw = ((ks * 4 + quad) ^ fr7) * 8;
            __builtin_amdgcn_s_setprio(1);
#pragma unroll
            for (int mi = 0; mi < 8; mi++) {
                const f16x8 af =
                    *(const f16x8*)(&Alds[buf][(mi * 16 + fr) * 64 + gsw]);
#pragma unroll
                for (int ni = 0; ni < 4; ni++)
                    acc[mi][ni] = __builtin_amdgcn_mfma_f32_16x16x32_f16(
                        af, bfr[ni], acc[mi][ni], 0, 0, 0);
            }
            __builtin_amdgcn_s_setprio(0);
        }
    };
    FETCH_B(0, 0);
    FETCH_SZ(0);
    STAGE(0, 0);
    STAGE(1, 1);
    CONV_SZ();
    asm volatile("s_waitcnt vmcnt(4)\n\ts_barrier" ::: "memory");
    for (int t = 0; t <= 60; t += 2) {
        FETCH_B(t + 1, 1);
        FETCH_SZ((t >> 1) + 1);
        COMPUTE(0, 0);
        asm volatile("s_barrier" ::: "memory");
        STAGE(0, t + 2);
        asm volatile("s_waitcnt vmcnt(20)\n\ts_barrier" ::: "memory");
        FETCH_B(t + 2, 0);
        COMPUTE(1, 1);
        CONV_SZ();
        asm volatile("s_barrier" ::: "memory");
        STAGE(1, t + 3);
        asm volatile("s_waitcnt vmcnt(12)\n\ts_barrier" ::: "memory");
    }
    FETCH_B(63, 1);
    COMPUTE(0, 0);
    asm volatile("s_waitcnt vmcnt(8)\n\ts_barrier" ::: "memory");
    COMPUTE(1, 1);
    const int cn = lane & 15, q4r = quad * 4;
#pragma unroll
    for (int ni = 0; ni < 4; ni++) {
        const int col = n0 + wid * 64 + ni * 16 + cn;
        const float bz = BIAS[col];
#pragma unroll
        for (int mi = 0; mi < 8; mi++) {
            const int rbase = m0 + mi * 16 + q4r;
#pragma unroll
            for (int r = 0; r < 4; r++)
                Y[(u64)(rbase + r) * N + col] = acc[mi][ni][r] + bz;
        }
    }
}

// =====================================================================
// Fallback (no ws): R1's verified kernel, unchanged (original inputs).
// =====================================================================
__global__ __launch_bounds__(256, 2) void gptq_gemm_fb(
    const float* __restrict__ X, const int* __restrict__ QW,
    const int* __restrict__ QZ, const float* __restrict__ SC,
    const float* __restrict__ BIAS, float* __restrict__ Y)
{
    constexpr int N = 4096, K = 4096, KB = 512, NT = 64;
    __shared__ __align__(16) u16 Alds[2][128 * 64];
    __shared__ __align__(16) u16 Blds[2][128 * 64];
    const int tid = threadIdx.x, lane = tid & 63, wid = tid >> 6;
    const int m0 = blockIdx.x * 128, n0 = blockIdx.y * 128;
    f32x4 acc[4][4];
#pragma unroll
    for (int i = 0; i < 4; i++)
#pragma unroll
        for (int j = 0; j < 4; j++) acc[i][j] = (f32x4){0.f, 0.f, 0.f, 0.f};
    const int wm = (wid >> 1) * 64, wn = (wid & 1) * 64;
    const int lrowA = tid >> 3;
    const float* gA = X + (u64)(m0 + lrowA) * K + (tid & 7) * 8;
    const int sA = ((tid & 7) ^ (lrowA & 7)) * 8;
    const int nl = tid >> 1, kq0 = (tid & 1) * 4;
    const int nglob = n0 + nl;
    const int* qrow = QW + (u64)nglob * KB;
    const int nl7 = nl & 7, zsh = (nglob & 7) * 4;
    const float* scp = SC + nglob;
    const int* qzp = QZ + (nglob >> 3);
    const int fr = lane & 15, quad = lane >> 4, fr7 = fr & 7;
    float4 af32[8];
    int4 q4;
    float sf;
    int zw;
    auto FETCH = [&](int t) {
        const int kt = t * 64;
#pragma unroll
        for (int i = 0; i < 4; i++) {
            const float* pa = gA + (u64)i * 32 * K + kt;
            af32[2 * i] = *(const float4*)pa;
            af32[2 * i + 1] = *(const float4*)(pa + 4);
        }
        q4 = *(const int4*)(qrow + (kt >> 3) + kq0);
        const int g = t >> 1;
        sf = scp[g * N];
        zw = qzp[g * (N / 8)];
    };
    auto STORE = [&](int buf) {
#pragma unroll
        for (int i = 0; i < 4; i++) {
            const float4 f0 = af32[2 * i], f1 = af32[2 * i + 1];
            uint4 w;
            w.x = cvt_pk(f0.x, f1.x); w.y = cvt_pk(f0.y, f1.y);
            w.z = cvt_pk(f0.z, f1.z); w.w = cvt_pk(f0.w, f1.w);
            *(uint4*)(&Alds[buf][(i * 32 + lrowA) * 64 + sA]) = w;
        }
        const int z = (zw >> zsh) & 0xF;
        const _Float16 hs = (_Float16)sf;
        const _Float16 hz = (_Float16)(float)(1024 + z);
        const f16x2 cs2 = {hs, hs}, cz2 = {hz, hz};
        const int qv[4] = {q4.x, q4.y, q4.z, q4.w};
#pragma unroll
        for (int c = 0; c < 4; c++) {
            const f16x8 wv = unpack_dq((u32)qv[c], cz2, cs2);
            const int gran = ((kq0 + c) ^ nl7) * 8;
            *(f16x8*)(&Blds[buf][nl * 64 + gran]) = wv;
        }
    };
    auto COMPUTE = [&](int buf) {
#pragma unroll
        for (int ks = 0; ks < 2; ks++) {
            const int gsw = ((ks * 4 + quad) ^ fr7) * 8;
            f16x8 af[4], bfr[4];
#pragma unroll
            for (int i = 0; i < 4; i++)
                af[i] = *(const f16x8*)(&Alds[buf][(wm + i * 16 + fr) * 64 + gsw]);
#pragma unroll
            for (int i = 0; i < 4; i++)
                bfr[i] = *(const f16x8*)(&Blds[buf][(wn + i * 16 + fr) * 64 + gsw]);
#pragma unroll
            for (int mi = 0; mi < 4; mi++)
#pragma unroll
                for (int ni = 0; ni < 4; ni++)
                    acc[mi][ni] = __builtin_amdgcn_mfma_f32_16x16x32_f16(
                        af[mi], bfr[ni], acc[mi][ni], 0, 0, 0);
        }
    };
    FETCH(0); STORE(0); __syncthreads();
#pragma unroll 2
    for (int t = 0; t < NT; ++t) {
        const int cur = t & 1;
        if (t + 1 < NT) FETCH(t + 1);
        COMPUTE(cur);
        if (t + 1 < NT) STORE(cur ^ 1);
        __syncthreads();
    }
    const int cn = lane & 15, q4r = quad * 4;
#pragma unroll
    for (int ni = 0; ni < 4; ni++) {
        const int col = n0 + wn + ni * 16 + cn;
        const float bz = BIAS[col];
#pragma unroll
        for (int mi = 0; mi < 4; mi++) {
            const int rbase = m0 + wm + mi * 16 + q4r;
#pragma unroll
            for (int r = 0; r < 4; r++)
                Y[(u64)(rbase + r) * N + col] = acc[mi][ni][r] + bz;
        }
    }
}

extern "C" void kernel_launch(void* const* d_in, const int* in_sizes, int n_in,
                              void* d_out, int out_size, void* d_ws, size_t ws_size,
                              hipStream_t stream) {
    const float* X    = (const float*)d_in[0];   // x       [2,4096,4096] f32
    const int*   QW   = (const int*)d_in[1];     // qweight [4096,512] int32
    const int*   QZ   = (const int*)d_in[2];     // qzeros  [32,512] int32
    const float* SC   = (const float*)d_in[3];   // scales  [32,4096] f32
    const float* BIAS = (const float*)d_in[4];   // bias    [4096] f32
    float* Y = (float*)d_out;                    // [8192,4096] f32

    const size_t needXh = (size_t)8192 * 4096 * sizeof(u16);       // 64 MiB
    const size_t needNew = needXh + (size_t)4096 * 4096 * 2;       // + 32 MiB
    const size_t needMid = needXh + (size_t)512 * 4096 * 4;        // + 8 MiB
    if (ws_size >= needNew) {
        u16* Xh = (u16*)d_ws;
        u16* Bt = (u16*)((char*)d_ws + needXh);
        gptq_prep_fused<<<4608, 256, 0, stream>>>(X, Xh, QW, QZ, SC, Bt);
        dim3 grid(64, 16, 1);                               // M/128 x N/256
        gptq_gemm_dq<<<grid, 256, 0, stream>>>(Xh, Bt, BIAS, Y);
    } else if (ws_size >= needMid) {
        u16* Xh  = (u16*)d_ws;
        int* QWt = (int*)((char*)d_ws + needXh);
        gptq_prep_fused<<<4096, 256, 0, stream>>>(X, Xh, QW, QZ, SC,
                                                  (u16*)nullptr);
        gptq_transpose<<<dim3(8, 64), 256, 0, stream>>>(QW, QWt);
        dim3 grid(64, 16, 1);                               // M/128 x N/256
        gptq_gemm_dma<<<grid, 256, 0, stream>>>(Xh, QWt, QZ, SC, BIAS, Y);
    } else {
        dim3 grid(64, 32, 1);                               // M/128 x N/128
        gptq_gemm_fb<<<grid, 256, 0, stream>>>(X, QW, QZ, SC, BIAS, Y);
    }
}